// Round 4
// baseline (12.737 us; speedup 1.0000x reference)
//
#include <hip/hip_runtime.h>

// TimeEncoder: out0[b,l,:] = W[:, idx] + bias  where idx = relu(floor(ts[b,l+1]-ts[b,l]))
//              out1[b,l]   = ts[b,l]
// B=64, L=8192, N_TIME=100, OUT_DIM=8, PER_TIME=1.0 (division is a no-op)

#define N_TIME 100
#define OUT_DIM 8
#define BB 64
#define LL 8192
#define BLOCK 256
#define EPT 4   // elements per thread

typedef __attribute__((ext_vector_type(4))) float fvec4;  // clang vector: OK for nontemporal builtins

__global__ __launch_bounds__(BLOCK) void time_encoder_kernel(
    const float* __restrict__ ts,    // [B, L+1]
    const float* __restrict__ W,     // [OUT_DIM, N_TIME] row-major
    const float* __restrict__ bias,  // [OUT_DIM]
    float* __restrict__ out_emb,     // [B*L, OUT_DIM]
    float* __restrict__ out_ts)      // [B*L]
{
    // Split table: T0[t] = W[0:4, t]+b[0:4], T1[t] = W[4:8, t]+b[4:8].
    // Row N_TIME = bias only (jax one_hot OOB row -> all-zero @ W + b).
    __shared__ __align__(16) fvec4 T0[N_TIME + 1];
    __shared__ __align__(16) fvec4 T1[N_TIME + 1];
    float* t0f = reinterpret_cast<float*>(T0);
    float* t1f = reinterpret_cast<float*>(T1);

    const int nthreads = gridDim.x * BLOCK;
    const int gid = blockIdx.x * BLOCK + threadIdx.x;

    // --- Issue all ts loads FIRST so their latency hides under the preload ---
    float x0[EPT], x1[EPT];
    #pragma unroll
    for (int e = 0; e < EPT; ++e) {
        int tid = gid + e * nthreads;
        int b = tid >> 13;                 // / 8192
        int l = tid & 8191;                // % 8192
        const float* row = ts + (size_t)b * (LL + 1);
        x0[e] = row[l];
        x1[e] = row[l + 1];
    }

    // --- Coalesced table preload (L2-resident after first block) ---
    for (int i = threadIdx.x; i < N_TIME * OUT_DIM; i += BLOCK) {
        int o = i / N_TIME;
        int t = i - o * N_TIME;
        float v = W[i] + bias[o];
        if (o < 4) t0f[t * 4 + o]       = v;
        else       t1f[t * 4 + (o - 4)] = v;
    }
    if (threadIdx.x < OUT_DIM) {           // OOB row = bias only
        int o = threadIdx.x;
        float v = bias[o];
        if (o < 4) t0f[N_TIME * 4 + o]       = v;
        else       t1f[N_TIME * 4 + (o - 4)] = v;
    }
    __syncthreads();

    // --- Gather + streaming stores ---
    #pragma unroll
    for (int e = 0; e < EPT; ++e) {
        int tid = gid + e * nthreads;      // grid-stride keeps stores coalesced
        int idx = (int)floorf(x1[e] - x0[e]);  // PER_TIME == 1.0
        idx = max(idx, 0);                 // relu
        idx = min(idx, N_TIME);            // OOB -> bias row

        fvec4 v0 = T0[idx];
        fvec4 v1 = T1[idx];

        fvec4* o4 = reinterpret_cast<fvec4*>(out_emb + (size_t)tid * OUT_DIM);
        __builtin_nontemporal_store(v0, o4);
        __builtin_nontemporal_store(v1, o4 + 1);
        __builtin_nontemporal_store(x0[e], out_ts + tid);
    }
}

extern "C" void kernel_launch(void* const* d_in, const int* in_sizes, int n_in,
                              void* d_out, int out_size, void* d_ws, size_t ws_size,
                              hipStream_t stream) {
    const float* ts   = (const float*)d_in[1];
    const float* W    = (const float*)d_in[2];
    const float* bias = (const float*)d_in[3];

    float* out_emb = (float*)d_out;                              // B*L*8 floats
    float* out_ts  = (float*)d_out + (size_t)BB * LL * OUT_DIM;  // B*L floats

    const int total = BB * LL;                 // 524288 elements
    const int grid  = total / (BLOCK * EPT);   // 512 blocks
    time_encoder_kernel<<<grid, BLOCK, 0, stream>>>(ts, W, bias, out_emb, out_ts);
}